// Round 3
// baseline (513.303 us; speedup 1.0000x reference)
//
#include <hip/hip_runtime.h>
#include <hip/hip_bf16.h>
#include <math.h>

// ---------------------------------------------------------------------------
// CRGainHopLayerAnnealed: n=8192, in_dim=256, out_dim=128, d_sub=64, K1=3
// 4-dispatch pipeline (no inter-block sync anywhere):
//   front : Hp = H@Wout^T (+bf16 HpT epi), Z_k = hop_k@W_k^T (+Gram partial
//           epi), P_k = Wout@W_k^T          [323 blocks, 8x4 micro, BM=128]
//   fused : blocks 0-2 smallk (Gpart reduce + logdet + Newton-Schulz inv)
//           blocks 3-514 split-K bf16 MFMA Pbuf[s]=(L@Hp)-partial, XCD-swz
//   qtw   : QT_k = s_k * P_k @ Minv_k  (+softmax weights + tail outputs)
//   back  : out = LN(softthresh(Hp + Z@QT^T - 0.15*sum_s Pbuf[s]))
// ---------------------------------------------------------------------------

#define COEFF 0.03125f        // d/(n*eps^2) = 64/(8192*0.25)
#define SCL_LAP (-0.15f)      // -ETA*LAMBDA_LAP

typedef __attribute__((ext_vector_type(8))) short short8;
typedef __attribute__((ext_vector_type(4))) float f32x4;

__device__ __forceinline__ unsigned short f2bf_bits(float f) {
  unsigned int u = __float_as_uint(f);
  unsigned int r = (u + 0x7fffu + ((u >> 16) & 1u)) >> 16;   // RNE
  return (unsigned short)r;
}

// ---------------- front: Hp (+HpT), Z (+Gram partial), P ------------------
// BM=128, BN=64, BK=16, 256 thr, 8x4 micro (VALU-bound: 3 b128 / 32 FMA).
__global__ __launch_bounds__(256) void front_kernel(
    const float* __restrict__ H, const float* __restrict__ hop,
    const float* __restrict__ Wst, const float* __restrict__ Wout,
    float* __restrict__ Hp, unsigned short* __restrict__ HpT,
    float* __restrict__ Zbuf, float* __restrict__ Gpart,
    float* __restrict__ Pb) {
  __shared__ __align__(16) float smem[8704];   // 34.8 KB (epilogue reuses)
  float* As = smem;          // [16][132] k-major
  float* Bs = smem + 2112;   // [16][68]  k-major
  const int tid = threadIdx.x;
  const int tx = tid & 15, ty = tid >> 4;
  const int b = blockIdx.x;

  const float* A;
  const float* B;
  int m0 = 0, k_id = 0, n_off = 0, mode;
  if (b < 192) {             // Z_k tile: 3 hops x 64 m-tiles
    mode = 0; k_id = b >> 6; m0 = (b & 63) * 128;
    A = hop + (size_t)k_id * 2097152;
    B = Wst + (size_t)k_id * 16384;
  } else if (b < 320) {      // Hp tile: 64 m-tiles x 2 n-tiles
    mode = 1; int i2 = b - 192;
    m0 = (i2 >> 1) * 128; n_off = (i2 & 1) * 64;
    A = H; B = Wout + (size_t)n_off * 256;
  } else {                   // P_k: one block per k
    mode = 2; k_id = b - 320; m0 = 0;
    A = Wout; B = Wst + (size_t)k_id * 16384;
  }

  float acc[8][4];
#pragma unroll
  for (int i = 0; i < 8; ++i)
#pragma unroll
    for (int j = 0; j < 4; ++j) acc[i][j] = 0.f;

  const int arow = tid >> 1, ak = (tid & 1) * 8;    // 128 rows x 16 k
  const int brow = tid >> 2, bk = (tid & 3) * 4;    // 64 rows x 16 k
  for (int k0 = 0; k0 < 256; k0 += 16) {
    float4 a0 = *(const float4*)(A + (size_t)(m0 + arow) * 256 + k0 + ak);
    float4 a1 = *(const float4*)(A + (size_t)(m0 + arow) * 256 + k0 + ak + 4);
    float4 bv = *(const float4*)(B + (size_t)brow * 256 + k0 + bk);
    __syncthreads();
    As[(ak + 0) * 132 + arow] = a0.x; As[(ak + 1) * 132 + arow] = a0.y;
    As[(ak + 2) * 132 + arow] = a0.z; As[(ak + 3) * 132 + arow] = a0.w;
    As[(ak + 4) * 132 + arow] = a1.x; As[(ak + 5) * 132 + arow] = a1.y;
    As[(ak + 6) * 132 + arow] = a1.z; As[(ak + 7) * 132 + arow] = a1.w;
    Bs[(bk + 0) * 68 + brow] = bv.x; Bs[(bk + 1) * 68 + brow] = bv.y;
    Bs[(bk + 2) * 68 + brow] = bv.z; Bs[(bk + 3) * 68 + brow] = bv.w;
    __syncthreads();
#pragma unroll
    for (int kk = 0; kk < 16; ++kk) {
      float4 x0 = *(const float4*)&As[kk * 132 + ty * 8];
      float4 x1 = *(const float4*)&As[kk * 132 + ty * 8 + 4];
      float4 y4 = *(const float4*)&Bs[kk * 68 + tx * 4];
      float a8[8] = {x0.x, x0.y, x0.z, x0.w, x1.x, x1.y, x1.z, x1.w};
      float b4[4] = {y4.x, y4.y, y4.z, y4.w};
#pragma unroll
      for (int i = 0; i < 8; ++i)
#pragma unroll
        for (int j = 0; j < 4; ++j) acc[i][j] = fmaf(a8[i], b4[j], acc[i][j]);
    }
  }
  __syncthreads();   // LDS free for epilogue reuse

  if (mode == 0) {
    // write Z + stage tile for Gram partial
#pragma unroll
    for (int i = 0; i < 8; ++i) {
      float4 v = {acc[i][0], acc[i][1], acc[i][2], acc[i][3]};
      *(float4*)(Zbuf + (size_t)(m0 + ty * 8 + i) * 192 + k_id * 64 + tx * 4) = v;
      *(float4*)&smem[(ty * 8 + i) * 68 + tx * 4] = v;
    }
    __syncthreads();
    float g[4][4];
#pragma unroll
    for (int i = 0; i < 4; ++i)
#pragma unroll
      for (int j = 0; j < 4; ++j) g[i][j] = 0.f;
    for (int r = 0; r < 128; ++r) {
      float4 zd4 = *(const float4*)&smem[r * 68 + ty * 4];
      float4 ze4 = *(const float4*)&smem[r * 68 + tx * 4];
      float zd[4] = {zd4.x, zd4.y, zd4.z, zd4.w};
      float ze[4] = {ze4.x, ze4.y, ze4.z, ze4.w};
#pragma unroll
      for (int i = 0; i < 4; ++i)
#pragma unroll
        for (int j = 0; j < 4; ++j) g[i][j] = fmaf(zd[i], ze[j], g[i][j]);
    }
    float* gp = Gpart + (size_t)(k_id * 64 + (b & 63)) * 4096;
#pragma unroll
    for (int i = 0; i < 4; ++i) {
      float4 v = {g[i][0], g[i][1], g[i][2], g[i][3]};
      *(float4*)(gp + (ty * 4 + i) * 64 + tx * 4) = v;
    }
  } else if (mode == 1) {
    // write fp32 Hp + stage for bf16 transpose
#pragma unroll
    for (int i = 0; i < 8; ++i) {
      float4 v = {acc[i][0], acc[i][1], acc[i][2], acc[i][3]};
      *(float4*)(Hp + (size_t)(m0 + ty * 8 + i) * 128 + n_off + tx * 4) = v;
      *(float4*)&smem[(ty * 8 + i) * 68 + tx * 4] = v;
    }
    __syncthreads();
    const int nn = tid >> 2, mc = (tid & 3) * 32;
    __attribute__((aligned(16))) unsigned short tmp[32];
#pragma unroll
    for (int mm = 0; mm < 32; ++mm) tmp[mm] = f2bf_bits(smem[(mc + mm) * 68 + nn]);
    unsigned short* dst = HpT + (size_t)(n_off + nn) * 8192 + m0 + mc;
    *(uint4*)(dst) = *(const uint4*)&tmp[0];
    *(uint4*)(dst + 8) = *(const uint4*)&tmp[8];
    *(uint4*)(dst + 16) = *(const uint4*)&tmp[16];
    *(uint4*)(dst + 24) = *(const uint4*)&tmp[24];
  } else {
    float* P = Pb + (size_t)k_id * 8192;
#pragma unroll
    for (int i = 0; i < 8; ++i) {
      float4 v = {acc[i][0], acc[i][1], acc[i][2], acc[i][3]};
      *(float4*)(P + (size_t)(ty * 8 + i) * 64 + tx * 4) = v;
    }
  }
}

// ---------------- fused-dispatch helpers (256 threads) ---------------------
__device__ __forceinline__ float blocksum256(float v, volatile float* scr) {
#pragma unroll
  for (int o = 32; o; o >>= 1) v += __shfl_xor(v, o);
  __syncthreads();
  if ((threadIdx.x & 63) == 0) scr[threadIdx.x >> 6] = v;
  __syncthreads();
  return scr[0] + scr[1] + scr[2] + scr[3];
}

// C = X * Y for 64x64 with X stored k-major (X[kk*64+row]): b128 only.
__device__ __forceinline__ void gemm64s(const float* X, const float* Y,
                                        float acc[4][4]) {
  const int tx = threadIdx.x & 15, ty = threadIdx.x >> 4;
#pragma unroll
  for (int i = 0; i < 4; ++i)
#pragma unroll
    for (int j = 0; j < 4; ++j) acc[i][j] = 0.f;
  for (int kk = 0; kk < 64; ++kk) {
    float4 a4 = *(const float4*)&X[kk * 64 + ty * 4];
    float4 b4 = *(const float4*)&Y[kk * 64 + tx * 4];
    float a[4] = {a4.x, a4.y, a4.z, a4.w};
    float bb[4] = {b4.x, b4.y, b4.z, b4.w};
#pragma unroll
    for (int i = 0; i < 4; ++i)
#pragma unroll
      for (int j = 0; j < 4; ++j) acc[i][j] = fmaf(a[i], bb[j], acc[i][j]);
  }
}

__device__ __forceinline__ void wb64(float* D, const float acc[4][4]) {
  const int tx = threadIdx.x & 15, ty = threadIdx.x >> 4;
#pragma unroll
  for (int i = 0; i < 4; ++i)
#pragma unroll
    for (int j = 0; j < 4; ++j) D[(ty * 4 + i) * 64 + tx * 4 + j] = acc[i][j];
}

__device__ __forceinline__ float dot64(const float* X, const float* Y, float* scr) {
  const int tx = threadIdx.x & 15, ty = threadIdx.x >> 4;
  float v = 0.f;
#pragma unroll
  for (int i = 0; i < 4; ++i)
#pragma unroll
    for (int j = 0; j < 4; ++j) {
      int idx = (ty * 4 + i) * 64 + tx * 4 + j;
      v += X[idx] * Y[idx];
    }
  return blocksum256(v, scr);
}

// ---------------- fused: split-K bf16 MFMA L@Hp  +  smallk -----------------
__global__ __launch_bounds__(256) void fused_big(
    const float* __restrict__ Lp, const unsigned short* __restrict__ HpT,
    float* __restrict__ Pbuf, const float* __restrict__ Gpart,
    float* __restrict__ Minv, float* __restrict__ Rout) {
  __shared__ __align__(16) float smem[12304];
  const int tid = threadIdx.x;

  if (blockIdx.x >= 3) {
    // ---------------- big GEMM path: BM=128,BN=128,BK=32 -------------------
    // XCD swizzle: split = g&7 so each XCD keeps one 256KB HpT chunk L2-hot.
    unsigned short (*As)[40] = (unsigned short(*)[40])smem;          // [128][40]
    unsigned short (*Bs)[40] = (unsigned short(*)[40])(smem + 2560); // [128][40]
    const int g = blockIdx.x - 3;
    const int split = g & 7;
    const int m0 = (g >> 3) * 128;
    const int kbase = split * 1024;
    const int wave = tid >> 6, lane = tid & 63;
    const int ar = tid >> 1, ah = (tid & 1) * 16;
    const size_t lrow = (size_t)(m0 + ar) * 8192;
    const size_t brow = (size_t)ar * 8192;
    f32x4 acc[2][8];
#pragma unroll
    for (int i = 0; i < 2; ++i)
#pragma unroll
      for (int j = 0; j < 8; ++j) acc[i][j] = (f32x4){0.f, 0.f, 0.f, 0.f};
    float4 apf[4];
    uint4 bpf[2];
    {
      const float* ap = Lp + lrow + kbase + ah;
      apf[0] = *(const float4*)(ap); apf[1] = *(const float4*)(ap + 4);
      apf[2] = *(const float4*)(ap + 8); apf[3] = *(const float4*)(ap + 12);
      const unsigned short* bp = HpT + brow + kbase + ah;
      bpf[0] = *(const uint4*)(bp); bpf[1] = *(const uint4*)(bp + 8);
    }
    const int quad = lane >> 4, mcol = lane & 15;
    for (int step = 0; step < 32; ++step) {
      __syncthreads();
      {
        __attribute__((aligned(16))) unsigned short tmp[16];
        const float* f = (const float*)apf;
#pragma unroll
        for (int i = 0; i < 16; ++i) tmp[i] = f2bf_bits(f[i]);
        *(uint4*)&As[ar][ah] = *(const uint4*)&tmp[0];
        *(uint4*)&As[ar][ah + 8] = *(const uint4*)&tmp[8];
        *(uint4*)&Bs[ar][ah] = bpf[0];
        *(uint4*)&Bs[ar][ah + 8] = bpf[1];
      }
      __syncthreads();
      if (step < 31) {  // prefetch next k-tile (overlaps MFMA)
        int kc = kbase + (step + 1) * 32;
        const float* ap = Lp + lrow + kc + ah;
        apf[0] = *(const float4*)(ap); apf[1] = *(const float4*)(ap + 4);
        apf[2] = *(const float4*)(ap + 8); apf[3] = *(const float4*)(ap + 12);
        const unsigned short* bp = HpT + brow + kc + ah;
        bpf[0] = *(const uint4*)(bp); bpf[1] = *(const uint4*)(bp + 8);
      }
      short8 af0 = *(const short8*)&As[wave * 32 + mcol][quad * 8];
      short8 af1 = *(const short8*)&As[wave * 32 + 16 + mcol][quad * 8];
#pragma unroll
      for (int nt = 0; nt < 8; ++nt) {
        short8 bf = *(const short8*)&Bs[nt * 16 + mcol][quad * 8];
        acc[0][nt] = __builtin_amdgcn_mfma_f32_16x16x32_bf16(af0, bf, acc[0][nt], 0, 0, 0);
        acc[1][nt] = __builtin_amdgcn_mfma_f32_16x16x32_bf16(af1, bf, acc[1][nt], 0, 0, 0);
      }
    }
    float* P = Pbuf + (size_t)split * 1048576;
#pragma unroll
    for (int mt = 0; mt < 2; ++mt)
#pragma unroll
      for (int nt = 0; nt < 8; ++nt)
#pragma unroll
        for (int r = 0; r < 4; ++r) {
          int grow = m0 + wave * 32 + mt * 16 + quad * 4 + r;
          int gcol = nt * 16 + mcol;
          P[(size_t)grow * 128 + gcol] = acc[mt][nt][r];
        }
    return;
  }

  // ---------------- smallk path: k = blockIdx.x ----------------------------
  const int k = blockIdx.x;
  float* B0 = smem;          // E
  float* B1 = smem + 4096;   // E2 -> X
  float* B2 = smem + 8192;   // E3 -> T
  float* scr = smem + 12288;
  // M = I + coeff * sum_b Gpart[k][b]   (64 partials, vectorized reduce)
  for (int i4 = tid * 4; i4 < 4096; i4 += 1024) {
    const float* gp = Gpart + (size_t)k * 64 * 4096 + i4;
    float s0 = 0.f, s1 = 0.f, s2 = 0.f, s3 = 0.f;
    for (int bb2 = 0; bb2 < 64; ++bb2) {
      float4 v = *(const float4*)(gp + (size_t)bb2 * 4096);
      s0 += v.x; s1 += v.y; s2 += v.z; s3 += v.w;
    }
    float sv[4] = {s0, s1, s2, s3};
#pragma unroll
    for (int e = 0; e < 4; ++e) {
      int i = i4 + e;
      B0[i] = COEFF * sv[e] + ((i >> 6) == (i & 63) ? 1.f : 0.f);
    }
  }
  __syncthreads();
  // Gershgorin bounds (wave 0; M symmetric, column==row sums)
  if (tid < 64) {
    float rs = 0.f, dg = B0[tid * 65];
    for (int j = 0; j < 64; ++j) rs += fabsf(B0[j * 64 + tid]);
    float lo = 2.f * dg - rs, hi = rs;
#pragma unroll
    for (int o = 32; o; o >>= 1) {
      lo = fminf(lo, __shfl_xor(lo, o));
      hi = fmaxf(hi, __shfl_xor(hi, o));
    }
    if (tid == 0) scr[4] = 0.5f * (fmaxf(lo, 1.f) + hi);
  }
  __syncthreads();
  const float alpha = scr[4], inva = 1.f / alpha;
  for (int i = tid; i < 4096; i += 256) {
    int r = i >> 6, c = i & 63;
    B0[i] = B0[i] * inva - (r == c ? 1.f : 0.f);   // E
  }
  __syncthreads();
  const int tx = tid & 15, ty = tid >> 4;
  float v1 = 0.f, v2 = 0.f;
#pragma unroll
  for (int i = 0; i < 4; ++i)
#pragma unroll
    for (int j = 0; j < 4; ++j) {
      int r = ty * 4 + i, c = tx * 4 + j;
      float e = B0[r * 64 + c];
      if (r == c) v1 += e;
      v2 += e * e;
    }
  float t1 = blocksum256(v1, scr);
  float t2 = blocksum256(v2, scr);
  float acc[4][4];
  gemm64s(B0, B0, acc); __syncthreads(); wb64(B1, acc); __syncthreads();  // E2
  float t3 = dot64(B1, B0, scr);
  float t4 = dot64(B1, B1, scr);
  gemm64s(B1, B0, acc); __syncthreads(); wb64(B2, acc); __syncthreads();  // E3
  float t5 = dot64(B2, B1, scr);
  float t6 = dot64(B2, B2, scr);
  gemm64s(B1, B1, acc);                                                   // E4 (regs)
  {
    float v7 = 0.f, v8 = 0.f;
#pragma unroll
    for (int i = 0; i < 4; ++i)
#pragma unroll
      for (int j = 0; j < 4; ++j) {
        int idx = (ty * 4 + i) * 64 + tx * 4 + j;
        v7 += acc[i][j] * B2[idx];
        v8 += acc[i][j] * acc[i][j];
      }
    float t7 = blocksum256(v7, scr);
    float t8 = blocksum256(v8, scr);
    if (tid == 0) {
      float ld = 64.f * logf(alpha) + t1 - t2 * 0.5f + t3 / 3.f - t4 * 0.25f
                 + t5 * 0.2f - t6 / 6.f + t7 / 7.f - t8 * 0.125f;
      Rout[k] = 0.5f * ld;
    }
  }
  // Newton-Schulz: X0 = I - E ; X <- X(2I - (I+E)X), 2 iters
  for (int i = tid; i < 4096; i += 256) {
    int r = i >> 6, c = i & 63;
    B1[i] = (r == c ? 1.f : 0.f) - B0[i];
  }
  __syncthreads();
  for (int it = 0; it < 2; ++it) {
    gemm64s(B0, B1, acc);       // E*X
    __syncthreads();
    {                           // T = E*X + X -> B2 (own elements)
#pragma unroll
      for (int i = 0; i < 4; ++i)
#pragma unroll
        for (int j = 0; j < 4; ++j) {
          int idx = (ty * 4 + i) * 64 + tx * 4 + j;
          B2[idx] = acc[i][j] + B1[idx];
        }
    }
    __syncthreads();
    gemm64s(B1, B2, acc);       // X*T
    __syncthreads();
    {                           // X = 2X - X*T (own elements)
#pragma unroll
      for (int i = 0; i < 4; ++i)
#pragma unroll
        for (int j = 0; j < 4; ++j) {
          int idx = (ty * 4 + i) * 64 + tx * 4 + j;
          B1[idx] = 2.f * B1[idx] - acc[i][j];
        }
    }
    __syncthreads();
  }
  for (int i = tid; i < 4096; i += 256) Minv[k * 4096 + i] = B1[i] * inva;
}

// ---------------- QT_k = s_k * P_k @ Minv_k  (+ weights + tail) ------------
__global__ __launch_bounds__(256) void qtw_kernel(
    const float* __restrict__ Pb, const float* __restrict__ Minv,
    const float* __restrict__ R, const float* __restrict__ tauP,
    float* __restrict__ QT, float* __restrict__ tail) {
  __shared__ __align__(16) float XT[4096];
  __shared__ __align__(16) float Y[4096];
  __shared__ float wsh;
  const int tid = threadIdx.x;
  const int k = blockIdx.x >> 1;
  const int m0 = (blockIdx.x & 1) * 64;
  if (tid == 0) {
    float R0 = R[0], R1 = R[1], R2 = R[2];
    float d0 = R0, d1 = R1 - R0, d2 = R2 - R1;
    float mean = (d0 + d1 + d2) * (1.f / 3.f);
    float e0 = d0 - mean, e1 = d1 - mean, e2 = d2 - mean;
    float sd = sqrtf((e0 * e0 + e1 * e1 + e2 * e2) * 0.5f) + 1e-6f;
    float n0 = e0 / sd, n1 = e1 / sd, n2 = e2 / sd;
    float tau = tauP[0];
    float x0 = n0 / tau, x1 = n1 / tau, x2 = n2 / tau;
    float mx = fmaxf(x0, fmaxf(x1, x2));
    float w0 = expf(x0 - mx), w1 = expf(x1 - mx), w2 = expf(x2 - mx);
    float s = w0 + w1 + w2;
    w0 /= s; w1 /= s; w2 /= s;
    wsh = 0.015625f * (k == 0 ? w0 : (k == 1 ? w1 : w2));   // ETA*coeff*w_k
    if (blockIdx.x == 0) {
      tail[0] = w0; tail[1] = w1; tail[2] = w2;
      tail[3] = n0; tail[4] = n1; tail[5] = n2;
      tail[6] = d0; tail[7] = d1; tail[8] = d2;
    }
  }
  {
    const int m = tid >> 2, c4 = (tid & 3) << 4;
    const float* src = Pb + (size_t)k * 8192 + (size_t)(m0 + m) * 64 + c4;
#pragma unroll
    for (int t = 0; t < 16; t += 4) {
      float4 v = *(const float4*)(src + t);
      XT[(c4 + t) * 64 + m] = v.x;
      XT[(c4 + t + 1) * 64 + m] = v.y;
      XT[(c4 + t + 2) * 64 + m] = v.z;
      XT[(c4 + t + 3) * 64 + m] = v.w;
    }
    for (int t = tid * 4; t < 4096; t += 1024)
      *(float4*)&Y[t] = *(const float4*)(Minv + (size_t)k * 4096 + t);
  }
  __syncthreads();
  float acc[4][4];
  gemm64s(XT, Y, acc);
  const float s = wsh;
  const int tx = tid & 15, ty = tid >> 4;
#pragma unroll
  for (int i = 0; i < 4; ++i) {
    float4 v = {s * acc[i][0], s * acc[i][1], s * acc[i][2], s * acc[i][3]};
    *(float4*)(QT + (size_t)(m0 + ty * 4 + i) * 192 + k * 64 + tx * 4) = v;
  }
}

// ---- back: pre = Hp + Z@QT^T ; out = LN(softthresh(pre - 0.15*sum Pbuf)) --
// BM=32, BN=128, K=192, grid 256, 256 thr (micro 2x8).
__global__ __launch_bounds__(256) void back_kernel(
    const float* __restrict__ Zbuf, const float* __restrict__ QT,
    const float* __restrict__ Hp, const float* __restrict__ Pbuf,
    const float* __restrict__ thr, const float* __restrict__ gamma,
    const float* __restrict__ beta, float* __restrict__ out) {
  __shared__ __align__(16) float As[16][36];
  __shared__ __align__(16) float Bs[16][132];
  const int tid = threadIdx.x;
  const int tx = tid & 15, ty = tid >> 4;
  const int m0 = blockIdx.x * 32;
  float cc[2][8];
#pragma unroll
  for (int i = 0; i < 2; ++i)
#pragma unroll
    for (int j = 0; j < 8; ++j) cc[i][j] = 0.f;
  const int lr = tid >> 2, lc = (tid & 3) << 2;
  const int jr = tid >> 1, jc = (tid & 1) << 3;
  for (int k0 = 0; k0 < 192; k0 += 16) {
    if (tid < 128) {
      float4 av = *(const float4*)(Zbuf + (size_t)(m0 + lr) * 192 + k0 + lc);
      As[lc][lr] = av.x; As[lc + 1][lr] = av.y;
      As[lc + 2][lr] = av.z; As[lc + 3][lr] = av.w;
    }
    {
      const float* q = QT + (size_t)jr * 192 + k0 + jc;
      float4 b0 = *(const float4*)(q);
      float4 b1 = *(const float4*)(q + 4);
      Bs[jc][jr] = b0.x; Bs[jc + 1][jr] = b0.y;
      Bs[jc + 2][jr] = b0.z; Bs[jc + 3][jr] = b0.w;
      Bs[jc + 4][jr] = b1.x; Bs[jc + 5][jr] = b1.y;
      Bs[jc + 6][jr] = b1.z; Bs[jc + 7][jr] = b1.w;
    }
    __syncthreads();
#pragma unroll
    for (int kk = 0; kk < 16; ++kk) {
      float2 a2 = *(const float2*)&As[kk][ty * 2];
      float4 b4a = *(const float4*)&Bs[kk][tx * 8];
      float4 b4b = *(const float4*)&Bs[kk][tx * 8 + 4];
      float bb[8] = {b4a.x, b4a.y, b4a.z, b4a.w, b4b.x, b4b.y, b4b.z, b4b.w};
#pragma unroll
      for (int j = 0; j < 8; ++j) {
        cc[0][j] = fmaf(a2.x, bb[j], cc[0][j]);
        cc[1][j] = fmaf(a2.y, bb[j], cc[1][j]);
      }
    }
    __syncthreads();
  }
  // epilogue: + Hp + SCL_LAP*sum_s Pbuf -> softthresh -> LN (rows of 128)
  const float4 tA = *(const float4*)(thr + tx * 8);
  const float4 tB = *(const float4*)(thr + tx * 8 + 4);
  const float tv[8] = {fabsf(tA.x), fabsf(tA.y), fabsf(tA.z), fabsf(tA.w),
                       fabsf(tB.x), fabsf(tB.y), fabsf(tB.z), fabsf(tB.w)};
  const float4 gA = *(const float4*)(gamma + tx * 8);
  const float4 gB = *(const float4*)(gamma + tx * 8 + 4);
  const float gv[8] = {gA.x, gA.y, gA.z, gA.w, gB.x, gB.y, gB.z, gB.w};
  const float4 bA = *(const float4*)(beta + tx * 8);
  const float4 bB = *(const float4*)(beta + tx * 8 + 4);
  const float bv[8] = {bA.x, bA.y, bA.z, bA.w, bB.x, bB.y, bB.z, bB.w};
  float sres[2][8], mean[2], inv[2];
#pragma unroll
  for (int i = 0; i < 2; ++i) {
    const size_t off = (size_t)(m0 + ty * 2 + i) * 128 + tx * 8;
    float4 h0 = *(const float4*)(Hp + off);
    float4 h1 = *(const float4*)(Hp + off + 4);
    float p[8] = {0.f, 0.f, 0.f, 0.f, 0.f, 0.f, 0.f, 0.f};
#pragma unroll
    for (int sp = 0; sp < 8; ++sp) {
      const float* pb = Pbuf + (size_t)sp * 1048576 + off;
      float4 q0 = *(const float4*)(pb);
      float4 q1 = *(const float4*)(pb + 4);
      p[0] += q0.x; p[1] += q0.y; p[2] += q0.z; p[3] += q0.w;
      p[4] += q1.x; p[5] += q1.y; p[6] += q1.z; p[7] += q1.w;
    }
    const float hv[8] = {h0.x, h0.y, h0.z, h0.w, h1.x, h1.y, h1.z, h1.w};
    float sum = 0.f;
#pragma unroll
    for (int j = 0; j < 8; ++j) {
      float x = cc[i][j] + hv[j] + SCL_LAP * p[j];
      float a = fmaxf(fabsf(x) - tv[j], 0.f);
      float sx = (x >= 0.f) ? a : -a;
      sres[i][j] = sx;
      sum += sx;
    }
#pragma unroll
    for (int o = 1; o < 16; o <<= 1) sum += __shfl_xor(sum, o);
    mean[i] = sum * (1.f / 128.f);
    float ss = 0.f;
#pragma unroll
    for (int j = 0; j < 8; ++j) {
      float dd = sres[i][j] - mean[i];
      ss += dd * dd;
    }
#pragma unroll
    for (int o = 1; o < 16; o <<= 1) ss += __shfl_xor(ss, o);
    inv[i] = rsqrtf(ss * (1.f / 128.f) + 1e-5f);
  }
#pragma unroll
  for (int i = 0; i < 2; ++i) {
    const size_t off = (size_t)(m0 + ty * 2 + i) * 128 + tx * 8;
    float o8[8];
#pragma unroll
    for (int j = 0; j < 8; ++j)
      o8[j] = (sres[i][j] - mean[i]) * inv[i] * gv[j] + bv[j];
    float4 v0 = {o8[0], o8[1], o8[2], o8[3]};
    float4 v1 = {o8[4], o8[5], o8[6], o8[7]};
    *(float4*)(out + off) = v0;
    *(float4*)(out + off + 4) = v1;
  }
}

// ---------------------------------------------------------------------------
extern "C" void kernel_launch(void* const* d_in, const int* in_sizes, int n_in,
                              void* d_out, int out_size, void* d_ws, size_t ws_size,
                              hipStream_t stream) {
  const float* H = (const float*)d_in[0];
  const float* hop = (const float*)d_in[1];
  const float* L = (const float*)d_in[2];
  const float* Wst = (const float*)d_in[3];
  const float* Wout = (const float*)d_in[4];
  const float* thr = (const float*)d_in[5];
  const float* gamma = (const float*)d_in[6];
  const float* beta = (const float*)d_in[7];
  const float* tau = (const float*)d_in[8];
  float* out = (float*)d_out;

  float* ws = (float*)d_ws;
  float* Zbuf = ws;                       // [8192][192] packed Z (k*64+d)
  float* Hp = Zbuf + 1572864;             // [8192][128]
  float* Gpart = Hp + 1048576;            // [3][64][4096]
  float* Minv = Gpart + 786432;           // [3][64][64]
  float* Rb = Minv + 12288;               // [3]
  float* Pb = Rb + 16;                    // [3][128][64]
  float* QT = Pb + 24576;                 // [128][192] packed QT
  float* Pbuf = QT + 24576;               // [8][8192][128] split-K partials
  unsigned short* HpT = (unsigned short*)(Pbuf + 8388608);  // [128][8192] bf16

  // Hp (+HpT bf16), Z (+Gram partials), P  -- one launch, 8x4 micro
  front_kernel<<<dim3(323), 256, 0, stream>>>(H, hop, Wst, Wout,
                                              Hp, HpT, Zbuf, Gpart, Pb);
  // fused: smallk (blocks 0-2: reduce+logdet+inv) + split-K L@Hp (XCD-swz)
  fused_big<<<dim3(515), 256, 0, stream>>>(L, HpT, Pbuf, Gpart, Minv, Rb);
  // weights + QT + tail outputs
  qtw_kernel<<<dim3(6), 256, 0, stream>>>(Pb, Minv, Rb, tau, QT, out + 1048576);
  // pre + split-K reduce + soft-threshold + LayerNorm
  back_kernel<<<dim3(256), 256, 0, stream>>>(Zbuf, QT, Hp, Pbuf,
                                             thr, gamma, beta, out);

  (void)in_sizes; (void)n_in; (void)out_size; (void)ws_size;
}